// Round 1
// baseline (4822.355 us; speedup 1.0000x reference)
//
#include <hip/hip_runtime.h>

#define N_B   64
#define N_T   1000
#define N_IN  80
#define N_REC 512
#define N_OUT 20

__device__ __constant__ const float ALPHA = 0.9512294245007140f; // exp(-1/20)
__device__ __constant__ const float KAPPA = 0.9512294245007140f;
#define THR 1.0f

// ---------------------------------------------------------------------------
// Kernel A: wT[j][r] = w_rec[r][j], diagonal zeroed.  (1 MB, trivial)
// ---------------------------------------------------------------------------
__global__ void k_transpose(const float* __restrict__ w_rec, float* __restrict__ wT) {
    int i = blockIdx.x * blockDim.x + threadIdx.x;   // 0 .. 512*512-1
    int j = i >> 9;        // wT row  (source column)
    int r = i & 511;       // wT col  (source row)
    float v = w_rec[r * N_REC + j];
    wT[i] = (r == j) ? 0.0f : v;
}

// ---------------------------------------------------------------------------
// Kernel B: inj[(t-t0)*64 + b][r] = dot(x[b, t-1, :], w_in[r, :]) (masked) + noise[t, b, r]
// w_in row held in 80 registers per thread; x row is block-uniform (scalar loads).
// ---------------------------------------------------------------------------
__global__ __launch_bounds__(512, 2) void k_inj(
    const float* __restrict__ x, const float* __restrict__ w_in,
    const float* __restrict__ noise, const int* __restrict__ seq,
    float* __restrict__ inj, int t0, int t1)
{
    const int r = threadIdx.x;
    float wreg[N_IN];
#pragma unroll
    for (int i = 0; i < N_IN; ++i) wreg[i] = w_in[r * N_IN + i];

    const int P = (t1 - t0) * N_B;
    for (int p = blockIdx.x; p < P; p += gridDim.x) {
        int pt = p >> 6;         // p / 64
        int b  = p & 63;
        int t  = t0 + pt;        // global timestep (>=1)
        float acc = noise[((size_t)t * N_B + b) * N_REC + r];
        if (t - 1 < seq[b]) {
            const float* xr = x + ((size_t)b * N_T + (t - 1)) * N_IN;
#pragma unroll
            for (int i = 0; i < N_IN; ++i) acc = fmaf(wreg[i], xr[i], acc);
        }
        inj[(size_t)p * N_REC + r] = acc;
    }
}

// ---------------------------------------------------------------------------
// Kernel C: the sequential scan. One workgroup per batch, 256 threads,
// thread handles neurons 2*tid and 2*tid+1. Spike-driven gather from wT.
// Deterministic (ballot + prefix-popcount) spike-list build, no atomics.
// Supports chunked execution via state checkpoint in ws.
// ---------------------------------------------------------------------------
__global__ __launch_bounds__(256, 1) void k_scan(
    const float* __restrict__ wT, const float* __restrict__ inj,
    const float* __restrict__ w_out, float* __restrict__ out_vo,
    int t0, int t1,
    float* __restrict__ st_v, unsigned long long* __restrict__ st_zm,
    float* __restrict__ st_vo)
{
    const int b    = blockIdx.x;
    const int tid  = threadIdx.x;
    const int w    = tid >> 6;
    const int lane = tid & 63;

    __shared__ int lists[2][N_REC];
    __shared__ unsigned long long zmA[4], zmB[4];
    __shared__ int pcA[4], pcB[4];
    __shared__ float tmp[N_OUT][8];

    float v0, v1;
    int z0, z1;
    float vo = 0.0f;
    int n_prev = 0, cur = 0;

    if (t0 == 1) {
        v0 = 0.0f; v1 = 0.0f; z0 = 0; z1 = 0;
        // lists empty (n_prev = 0); zm written during first iteration
    } else {
        float2 sv = *((const float2*)(st_v + (size_t)b * N_REC) + tid);
        v0 = sv.x; v1 = sv.y;
        unsigned long long mA = st_zm[b * 8 + w];
        unsigned long long mB = st_zm[b * 8 + 4 + w];
        z0 = (int)((mA >> lane) & 1ull);
        z1 = (int)((mB >> lane) & 1ull);
        if (tid < 8) {
            unsigned long long m = st_zm[b * 8 + tid];
            if (tid < 4) zmA[tid] = m; else zmB[tid - 4] = m;
        }
        if (tid < N_OUT) vo = st_vo[b * N_OUT + tid];
        __syncthreads();
        unsigned long long b0 = zmA[w], b1 = zmB[w];
        if (lane == 0) { pcA[w] = __popcll(b0); pcB[w] = __popcll(b1); }
        __syncthreads();
        int base = 0, ntot = 0;
#pragma unroll
        for (int ww = 0; ww < 4; ++ww) {
            int s = pcA[ww] + pcB[ww];
            if (ww < w) base += s;
            ntot += s;
        }
        unsigned long long lt = (1ull << lane) - 1ull;
        if (z0) lists[0][base + __popcll(b0 & lt)] = 2 * tid;
        if (z1) lists[0][base + pcA[w] + __popcll(b1 & lt)] = 2 * tid + 1;
        n_prev = ntot;
        __syncthreads();
    }

    // preload inj for t0
    float2 injn = *((const float2*)(inj + ((size_t)0 * N_B + b) * N_REC) + tid);

    for (int t = t0; t < t1; ++t) {
        float2 injv = injn;

        // ---- finalize vo for step t-1 (tmp written before previous B2) ----
        if (t > t0 && tid < N_OUT) {
            float s = 0.0f;
#pragma unroll
            for (int c = 0; c < 8; ++c) s += tmp[tid][c];
            vo = KAPPA * vo + s;
            out_vo[((size_t)(t - 1) * N_B + b) * N_OUT + tid] = vo;
        }

        // ---- spike-driven gather: acc += column j of w_rec for active j ----
        float acc0 = 0.0f, acc1 = 0.0f;
        {
            const int n = n_prev;
            const int* lc = lists[cur];
            int k = 0;
            if (n >= 8) {
                float2 val[8];
#pragma unroll
                for (int u = 0; u < 8; ++u) {
                    int j = __builtin_amdgcn_readfirstlane(lc[u]);
                    val[u] = *((const float2*)(wT + (size_t)j * N_REC) + tid);
                }
                for (k = 8; k + 8 <= n; k += 8) {
                    float2 val2[8];
#pragma unroll
                    for (int u = 0; u < 8; ++u) {
                        int j = __builtin_amdgcn_readfirstlane(lc[k + u]);
                        val2[u] = *((const float2*)(wT + (size_t)j * N_REC) + tid);
                    }
#pragma unroll
                    for (int u = 0; u < 8; ++u) {
                        acc0 += val[u].x; acc1 += val[u].y; val[u] = val2[u];
                    }
                }
#pragma unroll
                for (int u = 0; u < 8; ++u) { acc0 += val[u].x; acc1 += val[u].y; }
            }
            for (; k < n; ++k) {
                int j = __builtin_amdgcn_readfirstlane(lc[k]);
                float2 wv = *((const float2*)(wT + (size_t)j * N_REC) + tid);
                acc0 += wv.x; acc1 += wv.y;
            }
        }

        // prefetch inj for t+1 (hidden behind next iteration)
        if (t + 1 < t1)
            injn = *((const float2*)(inj + ((size_t)(t + 1 - t0) * N_B + b) * N_REC) + tid);

        // ---- membrane update + threshold ----
        v0 = ALPHA * v0 + acc0 + injv.x - (z0 ? THR : 0.0f);
        v1 = ALPHA * v1 + acc1 + injv.y - (z1 ? THR : 0.0f);
        z0 = v0 > THR;
        z1 = v1 > THR;

        unsigned long long b0 = __ballot(z0);
        unsigned long long b1 = __ballot(z1);
        if (lane == 0) {
            zmA[w] = b0; zmB[w] = b1;
            pcA[w] = __popcll(b0); pcB[w] = __popcll(b1);
        }
        __syncthreads();   // B1: zm/pc visible; everyone done with lists[cur]

        // ---- build next spike list (deterministic order) ----
        int base = 0, ntot = 0;
#pragma unroll
        for (int ww = 0; ww < 4; ++ww) {
            int s = pcA[ww] + pcB[ww];
            if (ww < w) base += s;
            ntot += s;
        }
        {
            unsigned long long lt = (1ull << lane) - 1ull;
            int nxt = cur ^ 1;
            if (z0) lists[nxt][base + __popcll(b0 & lt)] = 2 * tid;
            if (z1) lists[nxt][base + pcA[w] + __popcll(b1 & lt)] = 2 * tid + 1;
        }

        // ---- vo partials: 160 threads walk the spike bitmask ----
        if (tid < N_OUT * 8) {
            int o = tid >> 3, c = tid & 7;
            int ww = c >> 1;
            unsigned long long m = (c & 1) ? zmB[ww] : zmA[ww];
            float s = 0.0f;
            const float* wo = w_out + (size_t)o * N_REC + (c & 1);
            while (m) {
                int l = __builtin_ctzll(m);
                m &= m - 1;
                s += wo[2 * ((ww << 6) + l)];
            }
            tmp[o][c] = s;
        }
        __syncthreads();   // B2: list + tmp complete
        cur ^= 1;
        n_prev = ntot;
    }

    // finalize vo for t1-1
    if (tid < N_OUT) {
        float s = 0.0f;
#pragma unroll
        for (int c = 0; c < 8; ++c) s += tmp[tid][c];
        vo = KAPPA * vo + s;
        out_vo[((size_t)(t1 - 1) * N_B + b) * N_OUT + tid] = vo;
    }

    // checkpoint state for next chunk (harmless on last chunk)
    {
        float2 sv; sv.x = v0; sv.y = v1;
        *((float2*)(st_v + (size_t)b * N_REC) + tid) = sv;
        if (lane == 0) {
            st_zm[b * 8 + w]     = zmA[w];
            st_zm[b * 8 + 4 + w] = zmB[w];
        }
        if (tid < N_OUT) st_vo[b * N_OUT + tid] = vo;
    }
}

// ---------------------------------------------------------------------------
// Kernel D: softmax over the 20 outputs; also writes the t=0 rows.
// out_sm is (B,T,20); vo_seq/out_vo0 is (T,B,20) (same buffer).
// ---------------------------------------------------------------------------
__global__ void k_softmax(const float* __restrict__ vo_seq,
                          float* __restrict__ out_sm,
                          float* __restrict__ out_vo0)
{
    int idx = blockIdx.x * blockDim.x + threadIdx.x;
    if (idx >= N_B * N_T) return;
    int b = idx / N_T;
    int t = idx - b * N_T;
    float vals[N_OUT];
    if (t == 0) {
#pragma unroll
        for (int o = 0; o < N_OUT; ++o) {
            vals[o] = 0.0f;
            out_vo0[(size_t)b * N_OUT + o] = 0.0f;   // vo[0] = zeros
        }
    } else {
#pragma unroll
        for (int o = 0; o < N_OUT; ++o)
            vals[o] = vo_seq[((size_t)t * N_B + b) * N_OUT + o];
    }
    float mx = vals[0];
#pragma unroll
    for (int o = 1; o < N_OUT; ++o) mx = fmaxf(mx, vals[o]);
    float s = 0.0f;
#pragma unroll
    for (int o = 0; o < N_OUT; ++o) { vals[o] = expf(vals[o] - mx); s += vals[o]; }
    float inv = 1.0f / s;
#pragma unroll
    for (int o = 0; o < N_OUT; ++o)
        out_sm[((size_t)b * N_T + t) * N_OUT + o] = vals[o] * inv;
}

// ---------------------------------------------------------------------------
extern "C" void kernel_launch(void* const* d_in, const int* in_sizes, int n_in,
                              void* d_out, int out_size, void* d_ws, size_t ws_size,
                              hipStream_t stream)
{
    (void)in_sizes; (void)n_in; (void)out_size;
    const float* x     = (const float*)d_in[0];
    const float* w_in  = (const float*)d_in[1];
    const float* w_rec = (const float*)d_in[2];
    const float* w_out = (const float*)d_in[3];
    const float* noise = (const float*)d_in[4];
    const int*   seq   = (const int*)d_in[5];

    float* out    = (float*)d_out;
    float* out_sm = out;                                   // (B,T,20)
    float* out_vo = out + (size_t)N_B * N_T * N_OUT;       // (T,B,20)

    char* ws = (char*)d_ws;
    float* wT = (float*)ws;
    size_t off = (size_t)N_REC * N_REC * sizeof(float);    // 1 MB
    float* st_v = (float*)(ws + off);                off += (size_t)N_B * N_REC * sizeof(float);
    unsigned long long* st_zm = (unsigned long long*)(ws + off); off += (size_t)N_B * 8 * sizeof(unsigned long long);
    float* st_vo = (float*)(ws + off);               off += (size_t)N_B * N_OUT * sizeof(float);
    off = (off + 255) & ~(size_t)255;
    float* inj = (float*)(ws + off);

    size_t avail = (ws_size > off) ? (ws_size - off) : 0;
    size_t step_bytes = (size_t)N_B * N_REC * sizeof(float);   // 128 KB per step
    long max_steps = (long)(avail / step_bytes);
    int tchunk = (int)((max_steps > (N_T - 1)) ? (N_T - 1) : max_steps);
    if (tchunk < 1) tchunk = 1;

    k_transpose<<<dim3((N_REC * N_REC) / 256), dim3(256), 0, stream>>>(w_rec, wT);

    for (int t0 = 1; t0 < N_T; t0 += tchunk) {
        int t1 = t0 + tchunk; if (t1 > N_T) t1 = N_T;
        k_inj<<<dim3(256), dim3(512), 0, stream>>>(x, w_in, noise, seq, inj, t0, t1);
        k_scan<<<dim3(N_B), dim3(256), 0, stream>>>(wT, inj, w_out, out_vo,
                                                    t0, t1, st_v, st_zm, st_vo);
    }

    k_softmax<<<dim3((N_B * N_T + 255) / 256), dim3(256), 0, stream>>>(out_vo, out_sm, out_vo);
}

// Round 2
// 4161.075 us; speedup vs baseline: 1.1589x; 1.1589x over previous
//
#include <hip/hip_runtime.h>

#define N_B   64
#define N_T   1000
#define N_IN  80
#define N_REC 512
#define N_OUT 20
#define THR 1.0f

constexpr float ALPHA = 0.9512294245007140f; // exp(-1/20)
constexpr float KAPPA = 0.9512294245007140f;

// ---------------------------------------------------------------------------
// Kernel A: wT[j][r] = w_rec[r][j], diagonal zeroed. 513 rows: row 512 is all
// zeros (dummy target for spike-list padding).
// ---------------------------------------------------------------------------
__global__ void k_transpose(const float* __restrict__ w_rec, float* __restrict__ wT) {
    int i = blockIdx.x * blockDim.x + threadIdx.x;   // 0 .. 513*512-1
    if (i >= 513 * N_REC) return;
    int j = i >> 9;        // wT row  (source column), 0..512
    int r = i & 511;       // wT col  (source row)
    float v = 0.0f;
    if (j < N_REC && r != j) v = w_rec[r * N_REC + j];
    wT[i] = v;
}

// ---------------------------------------------------------------------------
// Kernel B: inj[(t-t0)*64 + b][r] = dot(x[b, t-1, :], w_in[r, :]) (masked) + noise[t, b, r]
// ---------------------------------------------------------------------------
__global__ __launch_bounds__(512, 2) void k_inj(
    const float* __restrict__ x, const float* __restrict__ w_in,
    const float* __restrict__ noise, const int* __restrict__ seq,
    float* __restrict__ inj, int t0, int t1)
{
    const int r = threadIdx.x;
    float wreg[N_IN];
#pragma unroll
    for (int i = 0; i < N_IN; ++i) wreg[i] = w_in[r * N_IN + i];

    const int P = (t1 - t0) * N_B;
    for (int p = blockIdx.x; p < P; p += gridDim.x) {
        int pt = p >> 6;         // p / 64
        int b  = p & 63;
        int t  = t0 + pt;        // global timestep (>=1)
        float acc = noise[((size_t)t * N_B + b) * N_REC + r];
        if (t - 1 < seq[b]) {
            const float* xr = x + ((size_t)b * N_T + (t - 1)) * N_IN;
#pragma unroll
            for (int i = 0; i < N_IN; ++i) acc = fmaf(wreg[i], xr[i], acc);
        }
        inj[(size_t)p * N_REC + r] = acc;
    }
}

// ---------------------------------------------------------------------------
// Kernel C: sequential scan. One workgroup per batch, 512 threads (8 waves),
// thread owns neuron `tid`. Spike-driven gather from wT with a batch-8
// double-buffered load pipeline; list padded to a multiple of 8 with the
// dummy zero row (j = N_REC) so every batch is full.
// ---------------------------------------------------------------------------
__global__ __launch_bounds__(512, 1) void k_scan(
    const float* __restrict__ wT, const float* __restrict__ inj,
    const float* __restrict__ w_out, float* __restrict__ out_vo,
    int t0, int t1,
    float* __restrict__ st_v, unsigned long long* __restrict__ st_zm,
    float* __restrict__ st_vo)
{
    const int b    = blockIdx.x;
    const int tid  = threadIdx.x;
    const int w    = tid >> 6;     // wave 0..7
    const int lane = tid & 63;

    __shared__ int lists[2][N_REC + 8];
    __shared__ unsigned long long zm[8];
    __shared__ int pc[8];
    __shared__ float tmp[N_OUT][8];

    float v;
    int z;
    float vo = 0.0f;
    int n_prev = 0, cur = 0;

    if (t0 == 1) {
        v = 0.0f; z = 0;   // empty spike list; gather skipped on first step
    } else {
        v = st_v[(size_t)b * N_REC + tid];
        unsigned long long m = st_zm[b * 8 + w];
        z = (int)((m >> lane) & 1ull);
        if (tid < 8) zm[tid] = st_zm[b * 8 + tid];
        if (tid < N_OUT) vo = st_vo[b * N_OUT + tid];
        __syncthreads();
        unsigned long long bm = zm[w];
        if (lane == 0) pc[w] = __popcll(bm);
        __syncthreads();
        int base = 0, ntot = 0;
#pragma unroll
        for (int ww = 0; ww < 8; ++ww) {
            int s = pc[ww];
            if (ww < w) base += s;
            ntot += s;
        }
        unsigned long long lt = (1ull << lane) - 1ull;
        if (z) lists[0][base + __popcll(bm & lt)] = tid;
        if (tid < 8) lists[0][ntot + tid] = N_REC;   // pad with dummy row
        n_prev = ntot;
        __syncthreads();
    }

    // preload inj for t0 (nontemporal: don't evict wT from L2)
    float injn = __builtin_nontemporal_load(inj + ((size_t)0 * N_B + b) * N_REC + tid);

    for (int t = t0; t < t1; ++t) {
        float injv = injn;

        // ---- finalize vo for step t-1 (tmp written before previous B2) ----
        if (t > t0 && tid < N_OUT) {
            float s = 0.0f;
#pragma unroll
            for (int c = 0; c < 8; ++c) s += tmp[tid][c];
            vo = KAPPA * vo + s;
            out_vo[((size_t)(t - 1) * N_B + b) * N_OUT + tid] = vo;
        }

        // ---- spike-driven gather: acc += wT[j][tid] for active j ----
        float acc = 0.0f;
        {
            const int n = n_prev;
            if (n > 0) {
                const int* lc = lists[cur];
                const int nb = (n + 7) >> 3;           // full batches (padded)
                int   jA[8];
                float vA[8];
#pragma unroll
                for (int u = 0; u < 8; ++u) jA[u] = lc[u];
#pragma unroll
                for (int u = 0; u < 8; ++u) {
                    int j = __builtin_amdgcn_readfirstlane(jA[u]);
                    vA[u] = wT[(size_t)j * N_REC + tid];
                }
                for (int k = 1; k < nb; ++k) {
                    int jB[8];
#pragma unroll
                    for (int u = 0; u < 8; ++u) jB[u] = lc[k * 8 + u];
                    float vB[8];
#pragma unroll
                    for (int u = 0; u < 8; ++u) {
                        int j = __builtin_amdgcn_readfirstlane(jB[u]);
                        vB[u] = wT[(size_t)j * N_REC + tid];
                    }
#pragma unroll
                    for (int u = 0; u < 8; ++u) { acc += vA[u]; vA[u] = vB[u]; }
                }
#pragma unroll
                for (int u = 0; u < 8; ++u) acc += vA[u];
            }
        }

        // prefetch inj for t+1 (hidden behind this iteration's tail)
        if (t + 1 < t1)
            injn = __builtin_nontemporal_load(
                inj + ((size_t)(t + 1 - t0) * N_B + b) * N_REC + tid);

        // ---- membrane update + threshold ----
        v = ALPHA * v + acc + injv - (z ? THR : 0.0f);
        z = v > THR;

        unsigned long long bm = __ballot(z);
        if (lane == 0) { zm[w] = bm; pc[w] = __popcll(bm); }
        __syncthreads();   // B1: zm/pc visible; everyone done reading lists[cur]

        // ---- build next spike list (deterministic order) ----
        int base = 0, ntot = 0;
#pragma unroll
        for (int ww = 0; ww < 8; ++ww) {
            int s = pc[ww];
            if (ww < w) base += s;
            ntot += s;
        }
        {
            unsigned long long lt = (1ull << lane) - 1ull;
            int nxt = cur ^ 1;
            if (z) lists[nxt][base + __popcll(bm & lt)] = tid;
            if (tid < 8) lists[nxt][ntot + tid] = N_REC;   // pad with dummy row
        }

        // ---- vo partials: 160 threads walk the spike bitmasks ----
        if (tid < N_OUT * 8) {
            int o = tid >> 3, c = tid & 7;
            unsigned long long m = zm[c];
            float s = 0.0f;
            const float* wo = w_out + (size_t)o * N_REC + (c << 6);
            while (m) {
                int l = __builtin_ctzll(m);
                m &= m - 1;
                s += wo[l];
            }
            tmp[o][c] = s;
        }
        __syncthreads();   // B2: list + tmp complete
        cur ^= 1;
        n_prev = ntot;
    }

    // finalize vo for t1-1
    if (tid < N_OUT) {
        float s = 0.0f;
#pragma unroll
        for (int c = 0; c < 8; ++c) s += tmp[tid][c];
        vo = KAPPA * vo + s;
        out_vo[((size_t)(t1 - 1) * N_B + b) * N_OUT + tid] = vo;
    }

    // checkpoint state for next chunk (harmless on last chunk)
    st_v[(size_t)b * N_REC + tid] = v;
    if (lane == 0) st_zm[b * 8 + w] = zm[w];
    if (tid < N_OUT) st_vo[b * N_OUT + tid] = vo;
}

// ---------------------------------------------------------------------------
// Kernel D: softmax over the 20 outputs; also writes the t=0 rows.
// ---------------------------------------------------------------------------
__global__ void k_softmax(const float* __restrict__ vo_seq,
                          float* __restrict__ out_sm,
                          float* __restrict__ out_vo0)
{
    int idx = blockIdx.x * blockDim.x + threadIdx.x;
    if (idx >= N_B * N_T) return;
    int b = idx / N_T;
    int t = idx - b * N_T;
    float vals[N_OUT];
    if (t == 0) {
#pragma unroll
        for (int o = 0; o < N_OUT; ++o) {
            vals[o] = 0.0f;
            out_vo0[(size_t)b * N_OUT + o] = 0.0f;   // vo[0] = zeros
        }
    } else {
#pragma unroll
        for (int o = 0; o < N_OUT; ++o)
            vals[o] = vo_seq[((size_t)t * N_B + b) * N_OUT + o];
    }
    float mx = vals[0];
#pragma unroll
    for (int o = 1; o < N_OUT; ++o) mx = fmaxf(mx, vals[o]);
    float s = 0.0f;
#pragma unroll
    for (int o = 0; o < N_OUT; ++o) { vals[o] = expf(vals[o] - mx); s += vals[o]; }
    float inv = 1.0f / s;
#pragma unroll
    for (int o = 0; o < N_OUT; ++o)
        out_sm[((size_t)b * N_T + t) * N_OUT + o] = vals[o] * inv;
}

// ---------------------------------------------------------------------------
extern "C" void kernel_launch(void* const* d_in, const int* in_sizes, int n_in,
                              void* d_out, int out_size, void* d_ws, size_t ws_size,
                              hipStream_t stream)
{
    (void)in_sizes; (void)n_in; (void)out_size;
    const float* x     = (const float*)d_in[0];
    const float* w_in  = (const float*)d_in[1];
    const float* w_rec = (const float*)d_in[2];
    const float* w_out = (const float*)d_in[3];
    const float* noise = (const float*)d_in[4];
    const int*   seq   = (const int*)d_in[5];

    float* out    = (float*)d_out;
    float* out_sm = out;                                   // (B,T,20)
    float* out_vo = out + (size_t)N_B * N_T * N_OUT;       // (T,B,20)

    char* ws = (char*)d_ws;
    float* wT = (float*)ws;
    size_t off = (size_t)513 * N_REC * sizeof(float);      // 513 rows (row 512 = zeros)
    float* st_v = (float*)(ws + off);                off += (size_t)N_B * N_REC * sizeof(float);
    unsigned long long* st_zm = (unsigned long long*)(ws + off); off += (size_t)N_B * 8 * sizeof(unsigned long long);
    float* st_vo = (float*)(ws + off);               off += (size_t)N_B * N_OUT * sizeof(float);
    off = (off + 255) & ~(size_t)255;
    float* inj = (float*)(ws + off);

    size_t avail = (ws_size > off) ? (ws_size - off) : 0;
    size_t step_bytes = (size_t)N_B * N_REC * sizeof(float);   // 128 KB per step
    long max_steps = (long)(avail / step_bytes);
    int tchunk = (int)((max_steps > (N_T - 1)) ? (N_T - 1) : max_steps);
    if (tchunk < 1) tchunk = 1;

    k_transpose<<<dim3((513 * N_REC + 255) / 256), dim3(256), 0, stream>>>(w_rec, wT);

    for (int t0 = 1; t0 < N_T; t0 += tchunk) {
        int t1 = t0 + tchunk; if (t1 > N_T) t1 = N_T;
        k_inj<<<dim3(256), dim3(512), 0, stream>>>(x, w_in, noise, seq, inj, t0, t1);
        k_scan<<<dim3(N_B), dim3(512), 0, stream>>>(wT, inj, w_out, out_vo,
                                                    t0, t1, st_v, st_zm, st_vo);
    }

    k_softmax<<<dim3((N_B * N_T + 255) / 256), dim3(256), 0, stream>>>(out_vo, out_sm, out_vo);
}

// Round 3
// 2811.358 us; speedup vs baseline: 1.7153x; 1.4801x over previous
//
#include <hip/hip_runtime.h>

#define N_B   64
#define N_T   1000
#define N_IN  80
#define N_REC 512
#define N_OUT 20
#define THR 1.0f

constexpr float ALPHA = 0.9512294245007140f; // exp(-1/20)
constexpr float KAPPA = 0.9512294245007140f;

// ---------------------------------------------------------------------------
// Kernel A: wT[j][r] = w_rec[r][j], diagonal zeroed. 513 rows: row 512 is all
// zeros (dummy target for spike-list padding).
// ---------------------------------------------------------------------------
__global__ void k_transpose(const float* __restrict__ w_rec, float* __restrict__ wT) {
    int i = blockIdx.x * blockDim.x + threadIdx.x;   // 0 .. 513*512-1
    if (i >= 513 * N_REC) return;
    int j = i >> 9;        // wT row  (source column), 0..512
    int r = i & 511;       // wT col  (source row)
    float v = 0.0f;
    if (j < N_REC && r != j) v = w_rec[r * N_REC + j];
    wT[i] = v;
}

// ---------------------------------------------------------------------------
// Kernel B: inj[(t-t0)*64 + b][r] = dot(x[b,t-1,:], w_in[r,:]) (masked) + noise[t,b,r]
// ---------------------------------------------------------------------------
__global__ __launch_bounds__(512, 2) void k_inj(
    const float* __restrict__ x, const float* __restrict__ w_in,
    const float* __restrict__ noise, const int* __restrict__ seq,
    float* __restrict__ inj, int t0, int t1)
{
    const int r = threadIdx.x;
    float wreg[N_IN];
#pragma unroll
    for (int i = 0; i < N_IN; ++i) wreg[i] = w_in[r * N_IN + i];

    const int P = (t1 - t0) * N_B;
    for (int p = blockIdx.x; p < P; p += gridDim.x) {
        int pt = p >> 6;         // p / 64
        int b  = p & 63;
        int t  = t0 + pt;        // global timestep (>=1)
        float acc = noise[((size_t)t * N_B + b) * N_REC + r];
        if (t - 1 < seq[b]) {
            const float* xr = x + ((size_t)b * N_T + (t - 1)) * N_IN;
#pragma unroll
            for (int i = 0; i < N_IN; ++i) acc = fmaf(wreg[i], xr[i], acc);
        }
        inj[(size_t)p * N_REC + r] = acc;
    }
}

// ---------------------------------------------------------------------------
// Kernel C: sequential scan. One workgroup per batch, 512 threads (8 waves).
// Per step, 3 barrier phases:
//   A: spike-driven gather (4 row-groups x 128 threads x float4) -> tmp_part
//      + finalize vo(t-1)
//   B: reduce partials, membrane update, ballot, stage z as floats
//   C: build next spike list (byte offsets, padded to x32 with dummy row)
//      + dense vo partials (w_out in VGPRs, z broadcast from LDS)
// ---------------------------------------------------------------------------
__global__ __launch_bounds__(512, 1) void k_scan(
    const float* __restrict__ wT, const float* __restrict__ inj,
    const float* __restrict__ w_out, float* __restrict__ out_vo,
    int t0, int t1,
    float* __restrict__ st_v, unsigned long long* __restrict__ st_zm,
    float* __restrict__ st_vo)
{
    const int b    = blockIdx.x;
    const int tid  = threadIdx.x;
    const int w    = tid >> 6;       // wave 0..7
    const int lane = tid & 63;
    const int g    = tid >> 7;       // row-group 0..3
    const int c    = tid & 127;      // float4 chunk within row (neurons 4c..4c+3)
    const unsigned long long lt = (1ull << lane) - 1ull;
    const int DUMMY = N_REC << 11;   // byte offset of the all-zero row

    __shared__ int lists[N_REC];                 // byte offsets (j<<11), padded
    __shared__ unsigned long long zm[8];
    __shared__ int pc[8];
    __shared__ float4 tmp_part[4][128];          // gather partials per row-group
    __shared__ float tmp[N_OUT][16];             // vo partials
    __shared__ alignas(16) float zf[N_REC];      // z as floats

    // w_out slice in registers: thread (o = tid>>4, s = tid&15) owns
    // w_out[o][s*32 .. s*32+31]   (only tid < 320 meaningful)
    float wvo[32];
    {
        int o = tid >> 4, s = tid & 15;
        if (tid < 320) {
#pragma unroll
            for (int i = 0; i < 32; ++i)
                wvo[i] = w_out[(size_t)o * N_REC + s * 32 + i];
        } else {
#pragma unroll
            for (int i = 0; i < 32; ++i) wvo[i] = 0.0f;
        }
    }

    float v;
    int z;
    float vo = 0.0f;
    int npad = 0;

    if (t0 == 1) {
        v = 0.0f; z = 0;    // empty list; first gather skipped (npad = 0)
    } else {
        v = st_v[(size_t)b * N_REC + tid];
        unsigned long long m = st_zm[b * 8 + w];
        z = (int)((m >> lane) & 1ull);
        if (tid < 8) zm[tid] = st_zm[b * 8 + tid];
        if (tid < N_OUT) vo = st_vo[b * N_OUT + tid];
        __syncthreads();
        unsigned long long bm0 = zm[w];
        if (lane == 0) pc[w] = __popcll(bm0);
        __syncthreads();
        int basep = 0, ntot = 0;
#pragma unroll
        for (int ww = 0; ww < 8; ++ww) {
            int s_ = pc[ww];
            if (ww < w) basep += s_;
            ntot += s_;
        }
        if (z) lists[basep + __popcll(bm0 & lt)] = tid << 11;
        npad = (ntot + 31) & ~31;
        { int i = ntot + tid; if (i < npad) lists[i] = DUMMY; }
        __syncthreads();
    }

    // preload inj for t0 (nontemporal: don't evict wT from L2)
    float injn = __builtin_nontemporal_load(inj + ((size_t)0 * N_B + b) * N_REC + tid);

    for (int t = t0; t < t1; ++t) {
        float injv = injn;

        // ---- Phase A: finalize vo(t-1) + spike-driven gather ----
        if (t > t0 && tid < N_OUT) {
            float s = 0.0f;
#pragma unroll
            for (int cc = 0; cc < 16; ++cc) s += tmp[tid][cc];
            vo = KAPPA * vo + s;
            out_vo[((size_t)(t - 1) * N_B + b) * N_OUT + tid] = vo;
        }

        float4 acc; acc.x = 0.0f; acc.y = 0.0f; acc.z = 0.0f; acc.w = 0.0f;
        {
            const int q = npad >> 2;           // rows per group, multiple of 8
            if (q > 0) {
                const int* lc = lists + g * q;
                const int nb = q >> 3;
                int jv = lc[lane & 7];
                float4 vA[8];
#pragma unroll
                for (int u = 0; u < 8; ++u) {
                    int off = __builtin_amdgcn_readlane(jv, u);
                    vA[u] = *(const float4*)((const char*)wT + off + (c << 4));
                }
                for (int k = 1; k < nb; ++k) {
                    int jv2 = lc[(k << 3) + (lane & 7)];
                    float4 vB[8];
#pragma unroll
                    for (int u = 0; u < 8; ++u) {
                        int off = __builtin_amdgcn_readlane(jv2, u);
                        vB[u] = *(const float4*)((const char*)wT + off + (c << 4));
                    }
#pragma unroll
                    for (int u = 0; u < 8; ++u) {
                        acc.x += vA[u].x; acc.y += vA[u].y;
                        acc.z += vA[u].z; acc.w += vA[u].w;
                        vA[u] = vB[u];
                    }
                }
#pragma unroll
                for (int u = 0; u < 8; ++u) {
                    acc.x += vA[u].x; acc.y += vA[u].y;
                    acc.z += vA[u].z; acc.w += vA[u].w;
                }
            }
        }
        tmp_part[g][c] = acc;

        // prefetch inj for t+1
        if (t + 1 < t1)
            injn = __builtin_nontemporal_load(
                inj + ((size_t)(t + 1 - t0) * N_B + b) * N_REC + tid);

        __syncthreads();   // B1: tmp_part complete, lists consumed

        // ---- Phase B: reduce + membrane update + ballot ----
        {
            const float* tp = (const float*)tmp_part;
            float accn = tp[tid] + tp[512 + tid] + tp[1024 + tid] + tp[1536 + tid];
            v = ALPHA * v + accn + injv - (z ? THR : 0.0f);
            z = v > THR;
            zf[tid] = z ? 1.0f : 0.0f;
        }
        unsigned long long bm = __ballot(z);
        if (lane == 0) { zm[w] = bm; pc[w] = __popcll(bm); }

        __syncthreads();   // B2: zm/pc/zf visible

        // ---- Phase C: build next list + dense vo partials ----
        {
            int basep = 0, ntot = 0;
#pragma unroll
            for (int ww = 0; ww < 8; ++ww) {
                int s_ = pc[ww];
                if (ww < w) basep += s_;
                ntot += s_;
            }
            if (z) lists[basep + __popcll(bm & lt)] = tid << 11;
            int npn = (ntot + 31) & ~31;
            { int i = ntot + tid; if (i < npn) lists[i] = DUMMY; }
            npad = npn;
        }
        if (tid < 320) {
            int o = tid >> 4, s = tid & 15;
            const float4* zp = ((const float4*)zf) + (s << 3);
            float sa = 0.0f;
#pragma unroll
            for (int i = 0; i < 8; ++i) {
                float4 zv = zp[i];
                sa = fmaf(wvo[4 * i + 0], zv.x, sa);
                sa = fmaf(wvo[4 * i + 1], zv.y, sa);
                sa = fmaf(wvo[4 * i + 2], zv.z, sa);
                sa = fmaf(wvo[4 * i + 3], zv.w, sa);
            }
            tmp[o][s] = sa;
        }

        __syncthreads();   // B3: list + tmp complete
    }

    // finalize vo for t1-1
    if (tid < N_OUT) {
        float s = 0.0f;
#pragma unroll
        for (int cc = 0; cc < 16; ++cc) s += tmp[tid][cc];
        vo = KAPPA * vo + s;
        out_vo[((size_t)(t1 - 1) * N_B + b) * N_OUT + tid] = vo;
    }

    // checkpoint state for next chunk (harmless on last chunk)
    st_v[(size_t)b * N_REC + tid] = v;
    if (lane == 0) st_zm[b * 8 + w] = zm[w];
    if (tid < N_OUT) st_vo[b * N_OUT + tid] = vo;
}

// ---------------------------------------------------------------------------
// Kernel D: softmax over the 20 outputs; also writes the t=0 rows.
// ---------------------------------------------------------------------------
__global__ void k_softmax(const float* __restrict__ vo_seq,
                          float* __restrict__ out_sm,
                          float* __restrict__ out_vo0)
{
    int idx = blockIdx.x * blockDim.x + threadIdx.x;
    if (idx >= N_B * N_T) return;
    int b = idx / N_T;
    int t = idx - b * N_T;
    float vals[N_OUT];
    if (t == 0) {
#pragma unroll
        for (int o = 0; o < N_OUT; ++o) {
            vals[o] = 0.0f;
            out_vo0[(size_t)b * N_OUT + o] = 0.0f;   // vo[0] = zeros
        }
    } else {
#pragma unroll
        for (int o = 0; o < N_OUT; ++o)
            vals[o] = vo_seq[((size_t)t * N_B + b) * N_OUT + o];
    }
    float mx = vals[0];
#pragma unroll
    for (int o = 1; o < N_OUT; ++o) mx = fmaxf(mx, vals[o]);
    float s = 0.0f;
#pragma unroll
    for (int o = 0; o < N_OUT; ++o) { vals[o] = expf(vals[o] - mx); s += vals[o]; }
    float inv = 1.0f / s;
#pragma unroll
    for (int o = 0; o < N_OUT; ++o)
        out_sm[((size_t)b * N_T + t) * N_OUT + o] = vals[o] * inv;
}

// ---------------------------------------------------------------------------
extern "C" void kernel_launch(void* const* d_in, const int* in_sizes, int n_in,
                              void* d_out, int out_size, void* d_ws, size_t ws_size,
                              hipStream_t stream)
{
    (void)in_sizes; (void)n_in; (void)out_size;
    const float* x     = (const float*)d_in[0];
    const float* w_in  = (const float*)d_in[1];
    const float* w_rec = (const float*)d_in[2];
    const float* w_out = (const float*)d_in[3];
    const float* noise = (const float*)d_in[4];
    const int*   seq   = (const int*)d_in[5];

    float* out    = (float*)d_out;
    float* out_sm = out;                                   // (B,T,20)
    float* out_vo = out + (size_t)N_B * N_T * N_OUT;       // (T,B,20)

    char* ws = (char*)d_ws;
    float* wT = (float*)ws;
    size_t off = (size_t)513 * N_REC * sizeof(float);      // 513 rows (row 512 = zeros)
    float* st_v = (float*)(ws + off);                off += (size_t)N_B * N_REC * sizeof(float);
    unsigned long long* st_zm = (unsigned long long*)(ws + off); off += (size_t)N_B * 8 * sizeof(unsigned long long);
    float* st_vo = (float*)(ws + off);               off += (size_t)N_B * N_OUT * sizeof(float);
    off = (off + 255) & ~(size_t)255;
    float* inj = (float*)(ws + off);

    size_t avail = (ws_size > off) ? (ws_size - off) : 0;
    size_t step_bytes = (size_t)N_B * N_REC * sizeof(float);   // 128 KB per step
    long max_steps = (long)(avail / step_bytes);
    int tchunk = (int)((max_steps > (N_T - 1)) ? (N_T - 1) : max_steps);
    if (tchunk < 1) tchunk = 1;

    k_transpose<<<dim3((513 * N_REC + 255) / 256), dim3(256), 0, stream>>>(w_rec, wT);

    for (int t0 = 1; t0 < N_T; t0 += tchunk) {
        int t1 = t0 + tchunk; if (t1 > N_T) t1 = N_T;
        k_inj<<<dim3(512), dim3(512), 0, stream>>>(x, w_in, noise, seq, inj, t0, t1);
        k_scan<<<dim3(N_B), dim3(512), 0, stream>>>(wT, inj, w_out, out_vo,
                                                    t0, t1, st_v, st_zm, st_vo);
    }

    k_softmax<<<dim3((N_B * N_T + 255) / 256), dim3(256), 0, stream>>>(out_vo, out_sm, out_vo);
}

// Round 4
// 2615.497 us; speedup vs baseline: 1.8438x; 1.0749x over previous
//
#include <hip/hip_runtime.h>

#define N_B   64
#define N_T   1000
#define N_IN  80
#define N_REC 512
#define N_OUT 20
#define THR 1.0f

constexpr float ALPHA = 0.9512294245007140f; // exp(-1/20)
constexpr float KAPPA = 0.9512294245007140f;

// ---------------------------------------------------------------------------
// Kernel A: wT[j][r] = w_rec[r][j], diagonal zeroed. 513 rows: row 512 is all
// zeros (dummy target for spike-list padding).
// ---------------------------------------------------------------------------
__global__ void k_transpose(const float* __restrict__ w_rec, float* __restrict__ wT) {
    int i = blockIdx.x * blockDim.x + threadIdx.x;   // 0 .. 513*512-1
    if (i >= 513 * N_REC) return;
    int j = i >> 9;        // wT row  (source column), 0..512
    int r = i & 511;       // wT col  (source row)
    float v = 0.0f;
    if (j < N_REC && r != j) v = w_rec[r * N_REC + j];
    wT[i] = v;
}

// ---------------------------------------------------------------------------
// Kernel B: inj[(t-t0)*64 + b][r] = dot(x[b,t-1,:], w_in[r,:]) (masked) + noise[t,b,r]
// Noise load double-buffered one iteration ahead (hides ~900 cy HBM latency).
// ---------------------------------------------------------------------------
__global__ __launch_bounds__(512, 2) void k_inj(
    const float* __restrict__ x, const float* __restrict__ w_in,
    const float* __restrict__ noise, const int* __restrict__ seq,
    float* __restrict__ inj, int t0, int t1)
{
    const int r = threadIdx.x;
    float wreg[N_IN];
#pragma unroll
    for (int i = 0; i < N_IN; ++i) wreg[i] = w_in[r * N_IN + i];

    const int P = (t1 - t0) * N_B;
    const int stride = gridDim.x;

    auto nz = [&](int p) -> float {
        int pt = p >> 6, b = p & 63, t = t0 + pt;
        return __builtin_nontemporal_load(noise + ((size_t)t * N_B + b) * N_REC + r);
    };

    int p = blockIdx.x;
    float nxt = (p < P) ? nz(p) : 0.0f;
    for (; p < P; p += stride) {
        float acc = nxt;
        if (p + stride < P) nxt = nz(p + stride);
        int pt = p >> 6;
        int b  = p & 63;
        int t  = t0 + pt;
        if (t - 1 < seq[b]) {
            const float* xr = x + ((size_t)b * N_T + (t - 1)) * N_IN;
#pragma unroll
            for (int i = 0; i < N_IN; ++i) acc = fmaf(wreg[i], xr[i], acc);
        }
        inj[(size_t)p * N_REC + r] = acc;
    }
}

// ---------------------------------------------------------------------------
// Kernel C: sequential scan. One workgroup per batch, 512 threads (8 waves).
// Per step t (z(t) from z(t-1)), 3 barrier phases:
//   A: spike gather for z(t-1) (4 row-groups x 128 thr x float4; list indices
//      fetched with ONE ds_read + readlane, batches purely vmcnt-pipelined)
//      + dense vo partials for z(t-1) (w_out in VGPRs, zfp padded rows)
//   B: reduce partials, membrane update, ballot, stage z(t) into zfp,
//      finalize + store vo(t-1)
//   C: build spike list for z(t) (byte offsets, padded to x32 with dummy row)
// LDS bank math: zfp row stride 36 floats -> bank group 4(s+i)%32 (<=2-way,
// free); tmp2 row stride 21 -> writer <=2-way, reader stride-1.
// ---------------------------------------------------------------------------
__global__ __launch_bounds__(512, 1) void k_scan(
    const float* __restrict__ wT, const float* __restrict__ inj,
    const float* __restrict__ w_out, float* __restrict__ out_vo,
    int t0, int t1,
    float* __restrict__ st_v, unsigned long long* __restrict__ st_zm,
    float* __restrict__ st_vo)
{
    const int b    = blockIdx.x;
    const int tid  = threadIdx.x;
    const int w    = tid >> 6;       // wave 0..7
    const int lane = tid & 63;
    const int g    = tid >> 7;       // row-group 0..3 (wave-uniform)
    const int c    = tid & 127;      // float4 chunk within row
    const unsigned long long lt = (1ull << lane) - 1ull;
    const int DUMMY = N_REC << 11;   // byte offset of the all-zero row

    __shared__ int lists[N_REC];                 // byte offsets (j<<11), padded
    __shared__ unsigned long long zm[8];
    __shared__ int pc[8];
    __shared__ float4 tmp_part[4][128];          // gather partials per group
    __shared__ float tmp2[16][21];               // vo partials [s][o], padded
    __shared__ alignas(16) float zfp[16 * 36];   // z floats, row s at s*36

    // w_out slice in registers: thread (o=tid>>4, s=tid&15) owns
    // w_out[o][s*32 .. s*32+31]  (tid < 320)
    float wvo[32];
    {
        int o = tid >> 4, s = tid & 15;
        if (tid < 320) {
#pragma unroll
            for (int i = 0; i < 32; ++i)
                wvo[i] = w_out[(size_t)o * N_REC + s * 32 + i];
        } else {
#pragma unroll
            for (int i = 0; i < 32; ++i) wvo[i] = 0.0f;
        }
    }

    float v;
    int z;
    float vo = 0.0f;
    int npad = 0;

    if (t0 == 1) {
        v = 0.0f; z = 0;    // empty list; first gather + vo-partial skipped
    } else {
        v = st_v[(size_t)b * N_REC + tid];
        unsigned long long m = st_zm[b * 8 + w];
        z = (int)((m >> lane) & 1ull);
        if (tid < 8) zm[tid] = st_zm[b * 8 + tid];
        if (tid < N_OUT) vo = st_vo[b * N_OUT + tid];
        __syncthreads();
        unsigned long long bm0 = zm[w];
        if (lane == 0) pc[w] = __popcll(bm0);
        __syncthreads();
        int basep = 0, ntot = 0;
#pragma unroll
        for (int ww = 0; ww < 8; ++ww) {
            int s_ = pc[ww];
            if (ww < w) basep += s_;
            ntot += s_;
        }
        if (z) lists[basep + __popcll(bm0 & lt)] = tid << 11;
        npad = (ntot + 31) & ~31;
        { int i = ntot + tid; if (i < npad) lists[i] = DUMMY; }
        __syncthreads();
    }

    // preload inj for t0 (nontemporal: don't evict wT from L2)
    float injn = __builtin_nontemporal_load(inj + ((size_t)0 * N_B + b) * N_REC + tid);

    for (int t = t0; t < t1; ++t) {
        float injv = injn;

        // ---- Phase A: spike gather + vo partials for z(t-1) ----
        float4 acc; acc.x = 0.0f; acc.y = 0.0f; acc.z = 0.0f; acc.w = 0.0f;
        {
            const int q = npad >> 2;             // rows per group (multiple of 8)
            if (q > 0) {
                // one LDS read covers the whole group's index list
                int jv  = lists[g * q + lane];
                int jv2 = (q > 64) ? lists[g * q + 64 + (lane & 63)] : 0;
                const char* wb = (const char*)wT + (c << 4);
                const int nb = q >> 3;
                float4 vA[8];
#pragma unroll
                for (int u = 0; u < 8; ++u) {
                    int off = __builtin_amdgcn_readlane(jv, u);
                    vA[u] = *(const float4*)(wb + off);
                }
                for (int k = 1; k < nb; ++k) {
                    float4 vB[8];
#pragma unroll
                    for (int u = 0; u < 8; ++u) {
                        int ug = (k << 3) + u;
                        int off = (ug < 64)
                            ? __builtin_amdgcn_readlane(jv,  ug)
                            : __builtin_amdgcn_readlane(jv2, ug - 64);
                        vB[u] = *(const float4*)(wb + off);
                    }
#pragma unroll
                    for (int u = 0; u < 8; ++u) {
                        acc.x += vA[u].x; acc.y += vA[u].y;
                        acc.z += vA[u].z; acc.w += vA[u].w;
                        vA[u] = vB[u];
                    }
                }
#pragma unroll
                for (int u = 0; u < 8; ++u) {
                    acc.x += vA[u].x; acc.y += vA[u].y;
                    acc.z += vA[u].z; acc.w += vA[u].w;
                }
            }
        }
        // vo partials for z(t-1) (zfp written in B of t-1; overlaps vmcnt waits)
        if (t > t0 && tid < 320) {
            int o = tid >> 4, s = tid & 15;
            const float4* zp = (const float4*)(zfp + s * 36);
            float sa = 0.0f;
#pragma unroll
            for (int i = 0; i < 8; ++i) {
                float4 zv = zp[i];
                sa = fmaf(wvo[4 * i + 0], zv.x, sa);
                sa = fmaf(wvo[4 * i + 1], zv.y, sa);
                sa = fmaf(wvo[4 * i + 2], zv.z, sa);
                sa = fmaf(wvo[4 * i + 3], zv.w, sa);
            }
            tmp2[s][o] = sa;
        }
        tmp_part[g][c] = acc;

        // prefetch inj for t+1
        if (t + 1 < t1)
            injn = __builtin_nontemporal_load(
                inj + ((size_t)(t + 1 - t0) * N_B + b) * N_REC + tid);

        __syncthreads();   // B1: tmp_part/tmp2 complete; zfp & lists consumed

        // ---- Phase B: reduce + membrane update + ballot + finalize vo(t-1) ----
        {
            const float* tp = (const float*)tmp_part;
            float accn = tp[tid] + tp[512 + tid] + tp[1024 + tid] + tp[1536 + tid];
            v = ALPHA * v + accn + injv - (z ? THR : 0.0f);
            z = v > THR;
            zfp[(tid >> 5) * 36 + (tid & 31)] = z ? 1.0f : 0.0f;
        }
        unsigned long long bm = __ballot(z);
        if (lane == 0) { zm[w] = bm; pc[w] = __popcll(bm); }
        if (t > t0 && tid < N_OUT) {
            float s = 0.0f;
#pragma unroll
            for (int ss = 0; ss < 16; ++ss) s += tmp2[ss][tid];
            vo = KAPPA * vo + s;
            out_vo[((size_t)(t - 1) * N_B + b) * N_OUT + tid] = vo;
        }
        __syncthreads();   // B2: zm/pc/zfp visible

        // ---- Phase C: build spike list for z(t) ----
        {
            int basep = 0, ntot = 0;
#pragma unroll
            for (int ww = 0; ww < 8; ++ww) {
                int s_ = pc[ww];
                if (ww < w) basep += s_;
                ntot += s_;
            }
            if (z) lists[basep + __popcll(bm & lt)] = tid << 11;
            int npn = (ntot + 31) & ~31;
            { int i = ntot + tid; if (i < npn) lists[i] = DUMMY; }
            npad = npn;
        }
        __syncthreads();   // B3: list complete
    }

    // ---- tail: vo partials + finalize for z(t1-1) ----
    if (tid < 320) {
        int o = tid >> 4, s = tid & 15;
        const float4* zp = (const float4*)(zfp + s * 36);
        float sa = 0.0f;
#pragma unroll
        for (int i = 0; i < 8; ++i) {
            float4 zv = zp[i];
            sa = fmaf(wvo[4 * i + 0], zv.x, sa);
            sa = fmaf(wvo[4 * i + 1], zv.y, sa);
            sa = fmaf(wvo[4 * i + 2], zv.z, sa);
            sa = fmaf(wvo[4 * i + 3], zv.w, sa);
        }
        tmp2[s][o] = sa;
    }
    __syncthreads();
    if (tid < N_OUT) {
        float s = 0.0f;
#pragma unroll
        for (int ss = 0; ss < 16; ++ss) s += tmp2[ss][tid];
        vo = KAPPA * vo + s;
        out_vo[((size_t)(t1 - 1) * N_B + b) * N_OUT + tid] = vo;
        st_vo[b * N_OUT + tid] = vo;
    }

    // checkpoint state for next chunk (harmless on last chunk)
    st_v[(size_t)b * N_REC + tid] = v;
    if (lane == 0) st_zm[b * 8 + w] = zm[w];
}

// ---------------------------------------------------------------------------
// Kernel D: softmax over the 20 outputs; also writes the t=0 rows.
// ---------------------------------------------------------------------------
__global__ void k_softmax(const float* __restrict__ vo_seq,
                          float* __restrict__ out_sm,
                          float* __restrict__ out_vo0)
{
    int idx = blockIdx.x * blockDim.x + threadIdx.x;
    if (idx >= N_B * N_T) return;
    int b = idx / N_T;
    int t = idx - b * N_T;
    float vals[N_OUT];
    if (t == 0) {
#pragma unroll
        for (int o = 0; o < N_OUT; ++o) {
            vals[o] = 0.0f;
            out_vo0[(size_t)b * N_OUT + o] = 0.0f;   // vo[0] = zeros
        }
    } else {
#pragma unroll
        for (int o = 0; o < N_OUT; ++o)
            vals[o] = vo_seq[((size_t)t * N_B + b) * N_OUT + o];
    }
    float mx = vals[0];
#pragma unroll
    for (int o = 1; o < N_OUT; ++o) mx = fmaxf(mx, vals[o]);
    float s = 0.0f;
#pragma unroll
    for (int o = 0; o < N_OUT; ++o) { vals[o] = expf(vals[o] - mx); s += vals[o]; }
    float inv = 1.0f / s;
#pragma unroll
    for (int o = 0; o < N_OUT; ++o)
        out_sm[((size_t)b * N_T + t) * N_OUT + o] = vals[o] * inv;
}

// ---------------------------------------------------------------------------
extern "C" void kernel_launch(void* const* d_in, const int* in_sizes, int n_in,
                              void* d_out, int out_size, void* d_ws, size_t ws_size,
                              hipStream_t stream)
{
    (void)in_sizes; (void)n_in; (void)out_size;
    const float* x     = (const float*)d_in[0];
    const float* w_in  = (const float*)d_in[1];
    const float* w_rec = (const float*)d_in[2];
    const float* w_out = (const float*)d_in[3];
    const float* noise = (const float*)d_in[4];
    const int*   seq   = (const int*)d_in[5];

    float* out    = (float*)d_out;
    float* out_sm = out;                                   // (B,T,20)
    float* out_vo = out + (size_t)N_B * N_T * N_OUT;       // (T,B,20)

    char* ws = (char*)d_ws;
    float* wT = (float*)ws;
    size_t off = (size_t)513 * N_REC * sizeof(float);      // 513 rows (row 512 = zeros)
    float* st_v = (float*)(ws + off);                off += (size_t)N_B * N_REC * sizeof(float);
    unsigned long long* st_zm = (unsigned long long*)(ws + off); off += (size_t)N_B * 8 * sizeof(unsigned long long);
    float* st_vo = (float*)(ws + off);               off += (size_t)N_B * N_OUT * sizeof(float);
    off = (off + 255) & ~(size_t)255;
    float* inj = (float*)(ws + off);

    size_t avail = (ws_size > off) ? (ws_size - off) : 0;
    size_t step_bytes = (size_t)N_B * N_REC * sizeof(float);   // 128 KB per step
    long max_steps = (long)(avail / step_bytes);
    int tchunk = (int)((max_steps > (N_T - 1)) ? (N_T - 1) : max_steps);
    if (tchunk < 1) tchunk = 1;

    k_transpose<<<dim3((513 * N_REC + 255) / 256), dim3(256), 0, stream>>>(w_rec, wT);

    for (int t0 = 1; t0 < N_T; t0 += tchunk) {
        int t1 = t0 + tchunk; if (t1 > N_T) t1 = N_T;
        k_inj<<<dim3(512), dim3(512), 0, stream>>>(x, w_in, noise, seq, inj, t0, t1);
        k_scan<<<dim3(N_B), dim3(512), 0, stream>>>(wT, inj, w_out, out_vo,
                                                    t0, t1, st_v, st_zm, st_vo);
    }

    k_softmax<<<dim3((N_B * N_T + 255) / 256), dim3(256), 0, stream>>>(out_vo, out_sm, out_vo);
}